// Round 14
// baseline (8832.679 us; speedup 1.0000x reference)
//
#include <hip/hip_runtime.h>
#include <math.h>

#define HD 512
#define TT 512
#define NB 128
#define NBLK 512          // 16 batch-groups x 32 unit-slices, 2 blocks/CU
#define NGRP 16
#define GBLK 32           // blocks per barrier group
#define NU 16             // units per block
#define NBB 8             // batches per group
#define NTHR 512
#define HBUF_N (NB * HD)  // floats per h buffer (256 KB)
#define SLOTP 64          // ints per flag slot (256 B)

typedef float v2f __attribute__((ext_vector_type(2)));
typedef float v4f __attribute__((ext_vector_type(4)));

__global__ void init_sync(int* s) {
    for (int i = threadIdx.x + blockIdx.x * 1024; i < NGRP * GBLK * SLOTP; i += 32768)
        s[i] = 0;
}

__device__ __forceinline__ float sigm(float v) { return 1.0f / (1.0f + __expf(-v)); }

// packed 2xf32 FMA / MUL (VOP3P)
__device__ __forceinline__ v2f pkfma(v2f a, v2f b, v2f c) {
    v2f d;
    asm("v_pk_fma_f32 %0, %1, %2, %3" : "=v"(d) : "v"(a), "v"(b), "v"(c));
    return d;
}
__device__ __forceinline__ v2f pkmul(v2f a, v2f b) {
    v2f d;
    asm("v_pk_mul_f32 %0, %1, %2" : "=v"(d) : "v"(a), "v"(b));
    return d;
}
__device__ __forceinline__ v2f vlo(v4f v) { return __builtin_shufflevector(v, v, 0, 1); }
__device__ __forceinline__ v2f vhi(v4f v) { return __builtin_shufflevector(v, v, 2, 3); }

// coherent (LLC) exchange: relaxed agent-scope, no fences (proven r3-r12)
#define H_LOAD(p)    __hip_atomic_load((p), __ATOMIC_RELAXED, __HIP_MEMORY_SCOPE_AGENT)
#define H_STORE(p,v) __hip_atomic_store((p), (v), __ATOMIC_RELAXED, __HIP_MEMORY_SCOPE_AGENT)

// merged butterfly (proven r8)
#define MERGE(A, B, bit)                                                        \
    ((((kq & (bit)) ? (B) : (A))) +                                             \
     __shfl_xor(((kq & (bit)) ? (A) : (B)), (bit)))

// wait for 16 producer flags [BASE..BASE+16) to reach `phase`
#define WAIT_HALF(BASE)                                                         \
  { if (tid < 16) {                                                             \
      const int* sl = gflags + ((BASE) + tid) * SLOTP;                          \
      while (H_LOAD(sl) < phase) __builtin_amdgcn_s_sleep(2);                   \
    }                                                                           \
    __syncthreads(); }

// stage 8 batches x 256 h (8 KB) of half HALF from hbuf parity PAR into hs
#define STAGE_H(PAR, HALF)                                                      \
  { const float* srcp = hbuf + (PAR) * HBUF_N + (size_t)b0 * HD + (HALF) * 256; \
    float vv[4];                                                                \
    _Pragma("unroll") for (int i = 0; i < 4; ++i) {                             \
      const int idx = i * NTHR + tid;                                           \
      vv[i] = H_LOAD(srcp + (idx >> 8) * HD + (idx & 255));                     \
    }                                                                           \
    _Pragma("unroll") for (int i = 0; i < 4; ++i) {                             \
      const int idx = i * NTHR + tid;                                           \
      hs[idx >> 8][(HALF) * 256 + (idx & 255)] = vv[i];                         \
    } }

// FMA over k-half A (k in [0,256)): chunks i=0,1 of the weight fragment
#define STEP_A                                                                  \
  _Pragma("unroll") for (int b = 0; b < NBB; ++b) {                             \
    v4f hb0 = *(const v4f*)&hs[b][4 * kq];                                      \
    v4f hb1 = *(const v4f*)&hs[b][4 * kq + 128];                                \
    _Pragma("unroll") for (int g = 0; g < 3; ++g) {                             \
      v2f t = pkmul(wW2[g][0], vlo(hb0));                                       \
      t = pkfma(wW2[g][1], vhi(hb0), t);                                        \
      t = pkfma(wW2[g][2], vlo(hb1), t);                                        \
      t = pkfma(wW2[g][3], vhi(hb1), t);                                        \
      a_[g][b] = t.x + t.y;                                                     \
    } }

// FMA over k-half B (k in [256,512)): chunks i=2,3
#define STEP_B                                                                  \
  _Pragma("unroll") for (int b = 0; b < NBB; ++b) {                             \
    v4f hb2 = *(const v4f*)&hs[b][4 * kq + 256];                                \
    v4f hb3 = *(const v4f*)&hs[b][4 * kq + 384];                                \
    _Pragma("unroll") for (int g = 0; g < 3; ++g) {                             \
      v2f t = pkmul(wW2[g][4], vlo(hb2));                                       \
      t = pkfma(wW2[g][5], vhi(hb2), t);                                        \
      t = pkfma(wW2[g][6], vlo(hb3), t);                                        \
      t = pkfma(wW2[g][7], vhi(hb3), t);                                        \
      a_[g][b] += t.x + t.y;                                                    \
    } }

// reduce + gates + store h (proven r8 tail)
#define STEP_FIN(XV, WBUF)                                                      \
  { float r_[3];                                                                \
    _Pragma("unroll") for (int g = 0; g < 3; ++g) {                             \
      const float m0 = MERGE(a_[g][0], a_[g][1], 1);                            \
      const float m1 = MERGE(a_[g][2], a_[g][3], 1);                            \
      const float m2 = MERGE(a_[g][4], a_[g][5], 1);                            \
      const float m3 = MERGE(a_[g][6], a_[g][7], 1);                            \
      const float n0 = MERGE(m0, m1, 2);                                        \
      const float n1 = MERGE(m2, m3, 2);                                        \
      float q = MERGE(n0, n1, 4);                                               \
      q += __shfl_xor(q, 8);                                                    \
      q += __shfl_xor(q, 16);                                                   \
      r_[g] = q;                                                                \
    }                                                                           \
    if (kq < NBB) {                                                             \
      const float xv = (XV);                                                    \
      const float r = sigm(fmaf(xv, wi_r, c_r) + r_[0]);                        \
      const float z = sigm(fmaf(xv, wi_z, c_z) + r_[1]);                        \
      const float n = tanhf(fmaf(xv, wi_n, bi_n) + r * (r_[2] + bh_n));         \
      const float hp = hs[kq][ur];                                              \
      H_STORE((WBUF) + (size_t)(b0 + kq) * HD + ur, fmaf(z, hp - n, n));        \
    } }

// drain h stores (syncthreads -> vmcnt(0)), then publish completion flag
#define FLAG_DONE()                                                             \
  { __syncthreads();                                                            \
    ++phase;                                                                    \
    if (tid == 0) H_STORE(myflag, phase); }

__global__ __launch_bounds__(NTHR, 2) void gru_persist(
    const float* __restrict__ x,
    const float* __restrict__ eWi, const float* __restrict__ eWh,
    const float* __restrict__ ebi, const float* __restrict__ ebh,
    const float* __restrict__ dWi, const float* __restrict__ dWh,
    const float* __restrict__ dbi, const float* __restrict__ dbh,
    const float* __restrict__ linW, const float* __restrict__ linb,
    float* __restrict__ hbuf, int* __restrict__ sync_w,
    float* __restrict__ out)
{
    const int blk = blockIdx.x;
    const int g   = blk >> 5;          // batch group 0..15
    const int us  = blk & 31;          // unit slice 0..31 (0-15 -> half A)
    const int b0  = g * NBB;
    const int u0  = us * NU;
    const int tid = threadIdx.x;
    const int u   = tid >> 5;          // 0..15 unit
    const int kq  = tid & 31;          // k lane
    const int ur  = u0 + u;

    __shared__ float hs[NBB][HD];      // staged h (8 x 512)
    __shared__ float xs[NBB][HD];      // prestaged encoder inputs x[b][t]
    __shared__ float lin_s[HD];
    __shared__ float y_s[NBB];

    int* gflags = sync_w + g * GBLK * SLOTP;
    int* myflag = gflags + us * SLOTP;
    int  phase  = 0;

    // encoder Wh fragment -> VGPRs as packed pairs (decoder loaded later)
    v2f wW2[3][8];
    #pragma unroll
    for (int g3 = 0; g3 < 3; ++g3) {
        const size_t row = (size_t)(g3 * HD + ur) * HD;
        #pragma unroll
        for (int i = 0; i < 4; ++i) {
            const v4f w = *(const v4f*)&eWh[row + i * 128 + 4 * kq];
            wW2[g3][2 * i]     = vlo(w);
            wW2[g3][2 * i + 1] = vhi(w);
        }
    }
    float wi_r = eWi[ur], wi_z = eWi[HD + ur], wi_n = eWi[2 * HD + ur];
    float c_r  = ebi[ur] + ebh[ur];
    float c_z  = ebi[HD + ur] + ebh[HD + ur];
    float bi_n = ebi[2 * HD + ur], bh_n = ebh[2 * HD + ur];
    lin_s[tid] = linW[tid];
    const float lb = linb[0];
    #pragma unroll
    for (int i = 0; i < NBB; ++i)       // prestage this group's x rows (16 KB)
        xs[i][tid] = x[(size_t)(b0 + i) * TT + tid];

    // ---------------- encoder step 0 (h = 0, no wait/stage) ----------------
    {
        #pragma unroll
        for (int i = 0; i < NBB; ++i) hs[i][tid] = 0.f;
        __syncthreads();
        float a_[3][NBB];
        STEP_A;
        STEP_B;
        STEP_FIN(xs[kq][0], hbuf);      // parity 0
        FLAG_DONE();
    }

    // ---------------- encoder steps 1..511 ----------------
    for (int s = 1; s < TT; ++s) {
        float a_[3][NBB];
        WAIT_HALF(0);
        STAGE_H((s + 1) & 1, 0);
        __syncthreads();
        STEP_A;                          // half-B wait hides under this
        WAIT_HALF(16);
        STAGE_H((s + 1) & 1, 1);
        __syncthreads();
        STEP_B;
        STEP_FIN(xs[kq][s], hbuf + (s & 1) * HBUF_N);
        FLAG_DONE();
    }

    // switch to decoder weights/params
    #pragma unroll
    for (int g3 = 0; g3 < 3; ++g3) {
        const size_t row = (size_t)(g3 * HD + ur) * HD;
        #pragma unroll
        for (int i = 0; i < 4; ++i) {
            const v4f w = *(const v4f*)&dWh[row + i * 128 + 4 * kq];
            wW2[g3][2 * i]     = vlo(w);
            wW2[g3][2 * i + 1] = vhi(w);
        }
    }
    wi_r = dWi[ur]; wi_z = dWi[HD + ur]; wi_n = dWi[2 * HD + ur];
    c_r  = dbi[ur] + dbh[ur];
    c_z  = dbi[HD + ur] + dbh[HD + ur];
    bi_n = dbi[2 * HD + ur]; bh_n = dbh[2 * HD + ur];

    // ---------------- decoder steps 0..512 ----------------
    for (int s = 0; s <= TT; ++s) {
        float a_[3][NBB];
        WAIT_HALF(0);
        STAGE_H((s + 1) & 1, 0);
        __syncthreads();
        if (s < TT) { STEP_A; }
        WAIT_HALF(16);
        STAGE_H((s + 1) & 1, 1);
        __syncthreads();
        // y[b] = hs[b] . linW + lb  (needs full hs; redundant per block)
        {
            const int b = tid >> 6, k64 = tid & 63;
            float p = 0.f;
            #pragma unroll
            for (int i = 0; i < 2; ++i) {
                const float4 hv = *(const float4*)&hs[b][4 * k64 + 256 * i];
                const float4 lv = *(const float4*)&lin_s[4 * k64 + 256 * i];
                p = fmaf(hv.x, lv.x, p); p = fmaf(hv.y, lv.y, p);
                p = fmaf(hv.z, lv.z, p); p = fmaf(hv.w, lv.w, p);
            }
            p += __shfl_xor(p, 1);  p += __shfl_xor(p, 2);  p += __shfl_xor(p, 4);
            p += __shfl_xor(p, 8);  p += __shfl_xor(p, 16); p += __shfl_xor(p, 32);
            if (k64 == 0) y_s[b] = p + lb;
        }
        if (s < TT) { STEP_B; }
        __syncthreads();                 // publish y_s
        if (s >= 1 && us == 0 && tid < NBB)
            out[(size_t)(b0 + tid) * TT + (TT - s)] = y_s[tid];
        if (s < TT) {
            STEP_FIN(y_s[kq], hbuf + (s & 1) * HBUF_N);
            FLAG_DONE();
        }
    }
}

extern "C" void kernel_launch(void* const* d_in, const int* in_sizes, int n_in,
                              void* d_out, int out_size, void* d_ws, size_t ws_size,
                              hipStream_t stream) {
    const float* x    = (const float*)d_in[0];
    const float* eWi  = (const float*)d_in[1];
    const float* eWh  = (const float*)d_in[2];
    const float* ebi  = (const float*)d_in[3];
    const float* ebh  = (const float*)d_in[4];
    const float* dWi  = (const float*)d_in[5];
    const float* dWh  = (const float*)d_in[6];
    const float* dbi  = (const float*)d_in[7];
    const float* dbh  = (const float*)d_in[8];
    const float* linW = (const float*)d_in[9];
    const float* linb = (const float*)d_in[10];
    float* out  = (float*)d_out;

    float* hbuf   = (float*)d_ws;                 // 2 x 256 KB h double-buffer
    int*   sync_w = (int*)(hbuf + 2 * HBUF_N);    // 16 x 32 x 256 B flag slots

    init_sync<<<32, 1024, 0, stream>>>(sync_w);
    gru_persist<<<dim3(NBLK), dim3(NTHR), 0, stream>>>(
        x, eWi, eWh, ebi, ebh, dWi, dWh, dbi, dbh, linW, linb,
        hbuf, sync_w, out);
}

// Round 15
// 7280.454 us; speedup vs baseline: 1.2132x; 1.2132x over previous
//
#include <hip/hip_runtime.h>
#include <math.h>

#define HD 512
#define TT 512
#define NB 128
#define NBLK 512          // 16 batch-groups x 32 unit-slices, 2 blocks/CU
#define NGRP 16
#define GBLK 32           // blocks per barrier group
#define NU 16             // units per block
#define NBB 8             // batches per group
#define NTHR 512
#define HBUF_N (NB * HD)  // floats per h buffer (256 KB)
#define SLOTP 64          // ints per flag slot (256 B)

typedef float v2f __attribute__((ext_vector_type(2)));
typedef float v4f __attribute__((ext_vector_type(4)));

__global__ void init_sync(int* s) {
    for (int i = threadIdx.x + blockIdx.x * 1024; i < NGRP * GBLK * SLOTP; i += 32768)
        s[i] = 0;
}

__device__ __forceinline__ float sigm(float v) { return 1.0f / (1.0f + __expf(-v)); }

// packed 2xf32 FMA / MUL (VOP3P)
__device__ __forceinline__ v2f pkfma(v2f a, v2f b, v2f c) {
    v2f d;
    asm("v_pk_fma_f32 %0, %1, %2, %3" : "=v"(d) : "v"(a), "v"(b), "v"(c));
    return d;
}
__device__ __forceinline__ v2f pkmul(v2f a, v2f b) {
    v2f d;
    asm("v_pk_mul_f32 %0, %1, %2" : "=v"(d) : "v"(a), "v"(b));
    return d;
}
__device__ __forceinline__ v2f vlo(v4f v) { return __builtin_shufflevector(v, v, 0, 1); }
__device__ __forceinline__ v2f vhi(v4f v) { return __builtin_shufflevector(v, v, 2, 3); }

// coherent (LLC) exchange: relaxed agent-scope, no fences (proven r3-r14)
#define H_LOAD(p)    __hip_atomic_load((p), __ATOMIC_RELAXED, __HIP_MEMORY_SCOPE_AGENT)
#define H_STORE(p,v) __hip_atomic_store((p), (v), __ATOMIC_RELAXED, __HIP_MEMORY_SCOPE_AGENT)

// merged butterfly (proven r8)
#define MERGE(A, B, bit)                                                        \
    ((((kq & (bit)) ? (B) : (A))) +                                             \
     __shfl_xor(((kq & (bit)) ? (A) : (B)), (bit)))

// wait for 16 producer flags [BASE..BASE+16) to reach `phase`
#define WAIT_HALF(BASE)                                                         \
  { if (tid < 16) {                                                             \
      const int* sl = gflags + ((BASE) + tid) * SLOTP;                          \
      while (H_LOAD(sl) < phase) __builtin_amdgcn_s_sleep(2);                   \
    }                                                                           \
    __syncthreads(); }

// stage 8 batches x 256 h (8 KB) of half HALF from hbuf parity PAR into hs
#define STAGE_H(PAR, HALF)                                                      \
  { const float* srcp = hbuf + (PAR) * HBUF_N + (size_t)b0 * HD + (HALF) * 256; \
    float vv[4];                                                                \
    _Pragma("unroll") for (int i = 0; i < 4; ++i) {                             \
      const int idx = i * NTHR + tid;                                           \
      vv[i] = H_LOAD(srcp + (idx >> 8) * HD + (idx & 255));                     \
    }                                                                           \
    _Pragma("unroll") for (int i = 0; i < 4; ++i) {                             \
      const int idx = i * NTHR + tid;                                           \
      hs[idx >> 8][(HALF) * 256 + (idx & 255)] = vv[i];                         \
    } }

// FMA over k-half A (k in [0,256)): chunks i=0,1 of the weight fragment
#define STEP_A                                                                  \
  _Pragma("unroll") for (int b = 0; b < NBB; ++b) {                             \
    v4f hb0 = *(const v4f*)&hs[b][4 * kq];                                      \
    v4f hb1 = *(const v4f*)&hs[b][4 * kq + 128];                                \
    _Pragma("unroll") for (int g = 0; g < 3; ++g) {                             \
      v2f t = pkmul(wW2[g][0], vlo(hb0));                                       \
      t = pkfma(wW2[g][1], vhi(hb0), t);                                        \
      t = pkfma(wW2[g][2], vlo(hb1), t);                                        \
      t = pkfma(wW2[g][3], vhi(hb1), t);                                        \
      a_[g][b] = t.x + t.y;                                                     \
    } }

// FMA over k-half B (k in [256,512)): chunks i=2,3
#define STEP_B                                                                  \
  _Pragma("unroll") for (int b = 0; b < NBB; ++b) {                             \
    v4f hb2 = *(const v4f*)&hs[b][4 * kq + 256];                                \
    v4f hb3 = *(const v4f*)&hs[b][4 * kq + 384];                                \
    _Pragma("unroll") for (int g = 0; g < 3; ++g) {                             \
      v2f t = pkmul(wW2[g][4], vlo(hb2));                                       \
      t = pkfma(wW2[g][5], vhi(hb2), t);                                        \
      t = pkfma(wW2[g][6], vlo(hb3), t);                                        \
      t = pkfma(wW2[g][7], vhi(hb3), t);                                        \
      a_[g][b] += t.x + t.y;                                                    \
    } }

// reduce + gates + store h (proven r8 tail)
#define STEP_FIN(XV, WBUF)                                                      \
  { float r_[3];                                                                \
    _Pragma("unroll") for (int g = 0; g < 3; ++g) {                             \
      const float m0 = MERGE(a_[g][0], a_[g][1], 1);                            \
      const float m1 = MERGE(a_[g][2], a_[g][3], 1);                            \
      const float m2 = MERGE(a_[g][4], a_[g][5], 1);                            \
      const float m3 = MERGE(a_[g][6], a_[g][7], 1);                            \
      const float n0 = MERGE(m0, m1, 2);                                        \
      const float n1 = MERGE(m2, m3, 2);                                        \
      float q = MERGE(n0, n1, 4);                                               \
      q += __shfl_xor(q, 8);                                                    \
      q += __shfl_xor(q, 16);                                                   \
      r_[g] = q;                                                                \
    }                                                                           \
    if (kq < NBB) {                                                             \
      const float xv = (XV);                                                    \
      const float r = sigm(fmaf(xv, wi_r, c_r) + r_[0]);                        \
      const float z = sigm(fmaf(xv, wi_z, c_z) + r_[1]);                        \
      const float n = tanhf(fmaf(xv, wi_n, bi_n) + r * (r_[2] + bh_n));         \
      const float hp = hs[kq][ur];                                              \
      H_STORE((WBUF) + (size_t)(b0 + kq) * HD + ur, fmaf(z, hp - n, n));        \
    } }

// drain h stores (syncthreads -> vmcnt(0)), then publish completion flag
#define FLAG_DONE()                                                             \
  { __syncthreads();                                                            \
    ++phase;                                                                    \
    if (tid == 0) H_STORE(myflag, phase); }

// (NTHR,4): empirically pins VGPR=64 (r8/r11/r12) -> 2 blocks/CU resident.
// The ~20 extra live values vs 64 are weight loads (rematerializable from
// L2-resident eWh/dWh) — r8 showed this costs little.
__global__ __launch_bounds__(NTHR, 4) void gru_persist(
    const float* __restrict__ x,
    const float* __restrict__ eWi, const float* __restrict__ eWh,
    const float* __restrict__ ebi, const float* __restrict__ ebh,
    const float* __restrict__ dWi, const float* __restrict__ dWh,
    const float* __restrict__ dbi, const float* __restrict__ dbh,
    const float* __restrict__ linW, const float* __restrict__ linb,
    float* __restrict__ hbuf, int* __restrict__ sync_w,
    float* __restrict__ out)
{
    const int blk = blockIdx.x;
    const int g   = blk >> 5;          // batch group 0..15
    const int us  = blk & 31;          // unit slice 0..31 (0-15 -> half A)
    const int b0  = g * NBB;
    const int u0  = us * NU;
    const int tid = threadIdx.x;
    const int u   = tid >> 5;          // 0..15 unit
    const int kq  = tid & 31;          // k lane
    const int ur  = u0 + u;

    __shared__ float hs[NBB][HD];      // staged h (8 x 512)
    __shared__ float xs[NBB][HD];      // prestaged encoder inputs x[b][t]
    __shared__ float lin_s[HD];
    __shared__ float y_s[NBB];

    int* gflags = sync_w + g * GBLK * SLOTP;
    int* myflag = gflags + us * SLOTP;
    int  phase  = 0;

    // encoder Wh fragment -> VGPRs as packed pairs (decoder loaded later)
    v2f wW2[3][8];
    #pragma unroll
    for (int g3 = 0; g3 < 3; ++g3) {
        const size_t row = (size_t)(g3 * HD + ur) * HD;
        #pragma unroll
        for (int i = 0; i < 4; ++i) {
            const v4f w = *(const v4f*)&eWh[row + i * 128 + 4 * kq];
            wW2[g3][2 * i]     = vlo(w);
            wW2[g3][2 * i + 1] = vhi(w);
        }
    }
    float wi_r = eWi[ur], wi_z = eWi[HD + ur], wi_n = eWi[2 * HD + ur];
    float c_r  = ebi[ur] + ebh[ur];
    float c_z  = ebi[HD + ur] + ebh[HD + ur];
    float bi_n = ebi[2 * HD + ur], bh_n = ebh[2 * HD + ur];
    lin_s[tid] = linW[tid];
    const float lb = linb[0];
    #pragma unroll
    for (int i = 0; i < NBB; ++i)       // prestage this group's x rows (16 KB)
        xs[i][tid] = x[(size_t)(b0 + i) * TT + tid];

    // ---------------- encoder step 0 (h = 0, no wait/stage) ----------------
    {
        #pragma unroll
        for (int i = 0; i < NBB; ++i) hs[i][tid] = 0.f;
        __syncthreads();
        float a_[3][NBB];
        STEP_A;
        STEP_B;
        STEP_FIN(xs[kq][0], hbuf);      // parity 0
        FLAG_DONE();
    }

    // ---------------- encoder steps 1..511 ----------------
    for (int s = 1; s < TT; ++s) {
        float a_[3][NBB];
        WAIT_HALF(0);
        STAGE_H((s + 1) & 1, 0);
        __syncthreads();
        STEP_A;                          // half-B wait hides under this
        WAIT_HALF(16);
        STAGE_H((s + 1) & 1, 1);
        __syncthreads();
        STEP_B;
        STEP_FIN(xs[kq][s], hbuf + (s & 1) * HBUF_N);
        FLAG_DONE();
    }

    // switch to decoder weights/params
    #pragma unroll
    for (int g3 = 0; g3 < 3; ++g3) {
        const size_t row = (size_t)(g3 * HD + ur) * HD;
        #pragma unroll
        for (int i = 0; i < 4; ++i) {
            const v4f w = *(const v4f*)&dWh[row + i * 128 + 4 * kq];
            wW2[g3][2 * i]     = vlo(w);
            wW2[g3][2 * i + 1] = vhi(w);
        }
    }
    wi_r = dWi[ur]; wi_z = dWi[HD + ur]; wi_n = dWi[2 * HD + ur];
    c_r  = dbi[ur] + dbh[ur];
    c_z  = dbi[HD + ur] + dbh[HD + ur];
    bi_n = dbi[2 * HD + ur]; bh_n = dbh[2 * HD + ur];

    // ---------------- decoder steps 0..512 ----------------
    for (int s = 0; s <= TT; ++s) {
        float a_[3][NBB];
        WAIT_HALF(0);
        STAGE_H((s + 1) & 1, 0);
        __syncthreads();
        if (s < TT) { STEP_A; }
        WAIT_HALF(16);
        STAGE_H((s + 1) & 1, 1);
        __syncthreads();
        // y[b] = hs[b] . linW + lb  (needs full hs; redundant per block)
        {
            const int b = tid >> 6, k64 = tid & 63;
            float p = 0.f;
            #pragma unroll
            for (int i = 0; i < 2; ++i) {
                const float4 hv = *(const float4*)&hs[b][4 * k64 + 256 * i];
                const float4 lv = *(const float4*)&lin_s[4 * k64 + 256 * i];
                p = fmaf(hv.x, lv.x, p); p = fmaf(hv.y, lv.y, p);
                p = fmaf(hv.z, lv.z, p); p = fmaf(hv.w, lv.w, p);
            }
            p += __shfl_xor(p, 1);  p += __shfl_xor(p, 2);  p += __shfl_xor(p, 4);
            p += __shfl_xor(p, 8);  p += __shfl_xor(p, 16); p += __shfl_xor(p, 32);
            if (k64 == 0) y_s[b] = p + lb;
        }
        if (s < TT) { STEP_B; }
        __syncthreads();                 // publish y_s
        if (s >= 1 && us == 0 && tid < NBB)
            out[(size_t)(b0 + tid) * TT + (TT - s)] = y_s[tid];
        if (s < TT) {
            STEP_FIN(y_s[kq], hbuf + (s & 1) * HBUF_N);
            FLAG_DONE();
        }
    }
}

extern "C" void kernel_launch(void* const* d_in, const int* in_sizes, int n_in,
                              void* d_out, int out_size, void* d_ws, size_t ws_size,
                              hipStream_t stream) {
    const float* x    = (const float*)d_in[0];
    const float* eWi  = (const float*)d_in[1];
    const float* eWh  = (const float*)d_in[2];
    const float* ebi  = (const float*)d_in[3];
    const float* ebh  = (const float*)d_in[4];
    const float* dWi  = (const float*)d_in[5];
    const float* dWh  = (const float*)d_in[6];
    const float* dbi  = (const float*)d_in[7];
    const float* dbh  = (const float*)d_in[8];
    const float* linW = (const float*)d_in[9];
    const float* linb = (const float*)d_in[10];
    float* out  = (float*)d_out;

    float* hbuf   = (float*)d_ws;                 // 2 x 256 KB h double-buffer
    int*   sync_w = (int*)(hbuf + 2 * HBUF_N);    // 16 x 32 x 256 B flag slots

    init_sync<<<32, 1024, 0, stream>>>(sync_w);
    gru_persist<<<dim3(NBLK), dim3(NTHR), 0, stream>>>(
        x, eWi, eWh, ebi, ebh, dWi, dWh, dbi, dbh, linW, linb,
        hbuf, sync_w, out);
}

// Round 16
// 6634.570 us; speedup vs baseline: 1.3313x; 1.0974x over previous
//
#include <hip/hip_runtime.h>
#include <math.h>

#define HD 512
#define TT 512
#define NB 128
#define NBLK 1024         // 32 batch-groups x 32 unit-slices, target 4 blocks/CU
#define NGRP 32
#define GBLK 32           // blocks per barrier group
#define NU 16             // units per block
#define NBB 4             // batches per group
#define NTHR 512
#define HBUF_N (NB * HD)  // floats per h buffer (256 KB)
#define SLOTP 64          // ints per flag slot (256 B)

typedef float v2f __attribute__((ext_vector_type(2)));
typedef float v4f __attribute__((ext_vector_type(4)));

__global__ void init_sync(int* s) {
    for (int i = threadIdx.x + blockIdx.x * 1024; i < NGRP * GBLK * SLOTP; i += 32768)
        s[i] = 0;
}

__device__ __forceinline__ float sigm(float v) { return 1.0f / (1.0f + __expf(-v)); }

// packed 2xf32 FMA / MUL (VOP3P) — halves the FMA issue count.
__device__ __forceinline__ v2f pkfma(v2f a, v2f b, v2f c) {
    v2f d;
    asm("v_pk_fma_f32 %0, %1, %2, %3" : "=v"(d) : "v"(a), "v"(b), "v"(c));
    return d;
}
__device__ __forceinline__ v2f pkmul(v2f a, v2f b) {
    v2f d;
    asm("v_pk_mul_f32 %0, %1, %2" : "=v"(d) : "v"(a), "v"(b));
    return d;
}
__device__ __forceinline__ v2f vlo(v4f v) { return __builtin_shufflevector(v, v, 0, 1); }
__device__ __forceinline__ v2f vhi(v4f v) { return __builtin_shufflevector(v, v, 2, 3); }

// coherent (LLC) exchange: relaxed agent-scope, no fences (proven r3-r15)
#define H_LOAD(p)    __hip_atomic_load((p), __ATOMIC_RELAXED, __HIP_MEMORY_SCOPE_AGENT)
#define H_STORE(p,v) __hip_atomic_store((p), (v), __ATOMIC_RELAXED, __HIP_MEMORY_SCOPE_AGENT)

// merged butterfly: lanes with kq&bit==0 keep A-chain, others B-chain;
// result lane l = sum over pair {l, l^bit} of (l&bit ? B : A)
#define MERGE(A, B, bit)                                                        \
    ((((kq & (bit)) ? (B) : (A))) +                                             \
     __shfl_xor(((kq & (bit)) ? (A) : (B)), (bit)))

// stage 4 batches x 512 h (8 KB, contiguous) — proven scalar form
#define STAGE(PAR)                                                              \
  { const float* srcp = hbuf + (PAR) * HBUF_N + (size_t)b0 * HD;                \
    float vv[NBB];                                                              \
    _Pragma("unroll") for (int i = 0; i < NBB; ++i)                             \
      vv[i] = H_LOAD(srcp + i * HD + tid);                                      \
    _Pragma("unroll") for (int i = 0; i < NBB; ++i) hs[i][tid] = vv[i]; }

// group barrier: 1 flag store + 32-lane parallel poll (no atomics, no fences)
#define GBAR()                                                                  \
  { __syncthreads();                                                            \
    ++phase;                                                                    \
    if (tid == 0) H_STORE(myflag, phase);                                       \
    if (tid < GBLK) {                                                           \
      const int* sl = gflags + tid * SLOTP;                                     \
      while (H_LOAD(sl) < phase) __builtin_amdgcn_s_sleep(2);                   \
    }                                                                           \
    __syncthreads(); }

// One GRU step for the (16u x 4b) slice. Thread: unit u, k-slice kq (16 k).
// wW2[g][2i],[2i+1] = Wh[g*512+ur][4kq+128i ..] as packed pairs.
// Merged butterfly leaves lane l holding gate sums for batch l&3.
#define STEP(XV, WBUF)                                                          \
  { float a_[3][NBB];                                                           \
    _Pragma("unroll") for (int b = 0; b < NBB; ++b) {                           \
      v4f hb0 = *(const v4f*)&hs[b][4 * kq];                                    \
      v4f hb1 = *(const v4f*)&hs[b][4 * kq + 128];                              \
      v4f hb2 = *(const v4f*)&hs[b][4 * kq + 256];                              \
      v4f hb3 = *(const v4f*)&hs[b][4 * kq + 384];                              \
      _Pragma("unroll") for (int g = 0; g < 3; ++g) {                           \
        v2f t = pkmul(wW2[g][0], vlo(hb0));                                     \
        t = pkfma(wW2[g][1], vhi(hb0), t);                                      \
        t = pkfma(wW2[g][2], vlo(hb1), t);                                      \
        t = pkfma(wW2[g][3], vhi(hb1), t);                                      \
        t = pkfma(wW2[g][4], vlo(hb2), t);                                      \
        t = pkfma(wW2[g][5], vhi(hb2), t);                                      \
        t = pkfma(wW2[g][6], vlo(hb3), t);                                      \
        t = pkfma(wW2[g][7], vhi(hb3), t);                                      \
        a_[g][b] = t.x + t.y;                                                   \
      } }                                                                       \
    float r_[3];                                                                \
    _Pragma("unroll") for (int g = 0; g < 3; ++g) {                             \
      const float m0 = MERGE(a_[g][0], a_[g][1], 1);                            \
      const float m1 = MERGE(a_[g][2], a_[g][3], 1);                            \
      float q = MERGE(m0, m1, 2);                                               \
      q += __shfl_xor(q, 4);                                                    \
      q += __shfl_xor(q, 8);                                                    \
      q += __shfl_xor(q, 16);                                                   \
      r_[g] = q;                                                                \
    }                                                                           \
    if (kq < NBB) {                                                             \
      const float xv = (XV);                                                    \
      const float r = sigm(fmaf(xv, wi_r, c_r) + r_[0]);                        \
      const float z = sigm(fmaf(xv, wi_z, c_z) + r_[1]);                        \
      const float n = tanhf(fmaf(xv, wi_n, bi_n) + r * (r_[2] + bh_n));         \
      const float hp = hs[kq][ur];                                              \
      H_STORE((WBUF) + (size_t)(b0 + kq) * HD + ur, fmaf(z, hp - n, n));        \
    } }

// (NTHR,4): VGPR cap 128; allocator's empirical fixed point on this code
// shape is 64 (r8/r11/r12/r15) -> 8 waves/SIMD -> 4 blocks/CU co-resident.
// Deadlock-safe if fewer fit: g=blk>>5 keeps groups contiguous, so complete
// groups run and retire in dispatch order (worst case serialization, no hang).
__global__ __launch_bounds__(NTHR, 4) void gru_persist(
    const float* __restrict__ x,
    const float* __restrict__ eWi, const float* __restrict__ eWh,
    const float* __restrict__ ebi, const float* __restrict__ ebh,
    const float* __restrict__ dWi, const float* __restrict__ dWh,
    const float* __restrict__ dbi, const float* __restrict__ dbh,
    const float* __restrict__ linW, const float* __restrict__ linb,
    float* __restrict__ hbuf, int* __restrict__ sync_w,
    float* __restrict__ out)
{
    const int blk = blockIdx.x;
    const int g   = blk >> 5;          // batch group 0..31
    const int us  = blk & 31;          // unit slice 0..31
    const int b0  = g * NBB;
    const int u0  = us * NU;
    const int tid = threadIdx.x;
    const int u   = tid >> 5;          // 0..15 unit
    const int kq  = tid & 31;          // k lane
    const int ur  = u0 + u;

    __shared__ float hs[NBB][HD];      // staged h (4 x 512)
    __shared__ float xs[NBB][HD];      // prestaged encoder inputs x[b][t]
    __shared__ float lin_s[HD];
    __shared__ float y_s[NBB];

    int* gflags = sync_w + g * GBLK * SLOTP;
    int* myflag = gflags + us * SLOTP;
    int  phase  = 0;

    // encoder Wh fragment -> VGPRs as packed pairs (decoder loaded later)
    v2f wW2[3][8];
    #pragma unroll
    for (int g3 = 0; g3 < 3; ++g3) {
        const size_t row = (size_t)(g3 * HD + ur) * HD;
        #pragma unroll
        for (int i = 0; i < 4; ++i) {
            const v4f w = *(const v4f*)&eWh[row + i * 128 + 4 * kq];
            wW2[g3][2 * i]     = vlo(w);
            wW2[g3][2 * i + 1] = vhi(w);
        }
    }
    float wi_r = eWi[ur], wi_z = eWi[HD + ur], wi_n = eWi[2 * HD + ur];
    float c_r  = ebi[ur] + ebh[ur];
    float c_z  = ebi[HD + ur] + ebh[HD + ur];
    float bi_n = ebi[2 * HD + ur], bh_n = ebh[2 * HD + ur];
    lin_s[tid] = linW[tid];
    const float lb = linb[0];
    #pragma unroll
    for (int i = 0; i < NBB; ++i)       // prestage this group's x rows (8 KB)
        xs[i][tid] = x[(size_t)(b0 + i) * TT + tid];

    // ---------------- encoder ----------------
    for (int s = 0; s < TT; ++s) {
        if (s == 0) {
            #pragma unroll
            for (int i = 0; i < NBB; ++i) hs[i][tid] = 0.f;
        } else {
            STAGE((s + 1) & 1);
        }
        __syncthreads();
        STEP(xs[kq][s], hbuf + (s & 1) * HBUF_N);
        GBAR();
    }

    // switch to decoder weights/params
    #pragma unroll
    for (int g3 = 0; g3 < 3; ++g3) {
        const size_t row = (size_t)(g3 * HD + ur) * HD;
        #pragma unroll
        for (int i = 0; i < 4; ++i) {
            const v4f w = *(const v4f*)&dWh[row + i * 128 + 4 * kq];
            wW2[g3][2 * i]     = vlo(w);
            wW2[g3][2 * i + 1] = vhi(w);
        }
    }
    wi_r = dWi[ur]; wi_z = dWi[HD + ur]; wi_n = dWi[2 * HD + ur];
    c_r  = dbi[ur] + dbh[ur];
    c_z  = dbi[HD + ur] + dbh[HD + ur];
    bi_n = dbi[2 * HD + ur]; bh_n = dbh[2 * HD + ur];

    // ---------------- decoder ----------------
    for (int s = 0; s <= TT; ++s) {
        STAGE((s + 1) & 1);
        __syncthreads();
        // y[b] = hs[b] . linW + lb  (4 batches x 64-lane dot, redundant/block)
        {
            const int b = tid >> 6, k64 = tid & 63;
            if (b < NBB) {
                float p = 0.f;
                #pragma unroll
                for (int i = 0; i < 2; ++i) {
                    const float4 hv = *(const float4*)&hs[b][4 * k64 + 256 * i];
                    const float4 lv = *(const float4*)&lin_s[4 * k64 + 256 * i];
                    p = fmaf(hv.x, lv.x, p); p = fmaf(hv.y, lv.y, p);
                    p = fmaf(hv.z, lv.z, p); p = fmaf(hv.w, lv.w, p);
                }
                p += __shfl_xor(p, 1);  p += __shfl_xor(p, 2);  p += __shfl_xor(p, 4);
                p += __shfl_xor(p, 8);  p += __shfl_xor(p, 16); p += __shfl_xor(p, 32);
                if (k64 == 0) y_s[b] = p + lb;
            }
        }
        __syncthreads();
        if (s >= 1 && us == 0 && tid < NBB)
            out[(size_t)(b0 + tid) * TT + (TT - s)] = y_s[tid];
        if (s < TT) {
            STEP(y_s[kq], hbuf + (s & 1) * HBUF_N);
            GBAR();
        }
    }
}

extern "C" void kernel_launch(void* const* d_in, const int* in_sizes, int n_in,
                              void* d_out, int out_size, void* d_ws, size_t ws_size,
                              hipStream_t stream) {
    const float* x    = (const float*)d_in[0];
    const float* eWi  = (const float*)d_in[1];
    const float* eWh  = (const float*)d_in[2];
    const float* ebi  = (const float*)d_in[3];
    const float* ebh  = (const float*)d_in[4];
    const float* dWi  = (const float*)d_in[5];
    const float* dWh  = (const float*)d_in[6];
    const float* dbi  = (const float*)d_in[7];
    const float* dbh  = (const float*)d_in[8];
    const float* linW = (const float*)d_in[9];
    const float* linb = (const float*)d_in[10];
    float* out  = (float*)d_out;

    float* hbuf   = (float*)d_ws;                 // 2 x 256 KB h double-buffer
    int*   sync_w = (int*)(hbuf + 2 * HBUF_N);    // 32 x 32 x 256 B flag slots

    init_sync<<<32, 1024, 0, stream>>>(sync_w);
    gru_persist<<<dim3(NBLK), dim3(NTHR), 0, stream>>>(
        x, eWi, eWh, ebi, ebh, dWi, dWh, dbi, dbh, linW, linb,
        hbuf, sync_w, out);
}

// Round 17
// 4466.672 us; speedup vs baseline: 1.9775x; 1.4853x over previous
//
#include <hip/hip_runtime.h>
#include <math.h>

#define HD 512
#define TT 512
#define NB 128
#define NBLK 512          // 16 batch-groups x 32 unit-slices, 2 blocks/CU
#define NGRP 16
#define GBLK 32           // blocks per barrier group
#define NU 16             // units per block
#define NBB 8             // batches per group
#define NTHR 512
#define HBUF_N (NB * HD)  // floats per h buffer (256 KB)
#define SLOTP 64          // ints per flag slot (256 B)

typedef float v2f __attribute__((ext_vector_type(2)));
typedef float v4f __attribute__((ext_vector_type(4)));

__global__ void init_sync(int* s) {
    for (int i = threadIdx.x + blockIdx.x * 1024; i < NGRP * GBLK * SLOTP; i += 32768)
        s[i] = 0;
}

__device__ __forceinline__ float sigm(float v) { return 1.0f / (1.0f + __expf(-v)); }

// packed 2xf32 FMA / MUL (VOP3P) — halves the FMA issue count.
__device__ __forceinline__ v2f pkfma(v2f a, v2f b, v2f c) {
    v2f d;
    asm("v_pk_fma_f32 %0, %1, %2, %3" : "=v"(d) : "v"(a), "v"(b), "v"(c));
    return d;
}
__device__ __forceinline__ v2f pkmul(v2f a, v2f b) {
    v2f d;
    asm("v_pk_mul_f32 %0, %1, %2" : "=v"(d) : "v"(a), "v"(b));
    return d;
}
__device__ __forceinline__ v2f vlo(v4f v) { return __builtin_shufflevector(v, v, 0, 1); }
__device__ __forceinline__ v2f vhi(v4f v) { return __builtin_shufflevector(v, v, 2, 3); }

// coherent (LLC) exchange: relaxed agent-scope, no fences (proven r3-r16)
#define H_LOAD(p)    __hip_atomic_load((p), __ATOMIC_RELAXED, __HIP_MEMORY_SCOPE_AGENT)
#define H_STORE(p,v) __hip_atomic_store((p), (v), __ATOMIC_RELAXED, __HIP_MEMORY_SCOPE_AGENT)

// merged butterfly: lanes with kq&bit==0 keep A-chain, others B-chain;
// result lane l = sum over pair {l, l^bit} of (l&bit ? B : A)
#define MERGE(A, B, bit)                                                        \
    ((((kq & (bit)) ? (B) : (A))) +                                             \
     __shfl_xor(((kq & (bit)) ? (A) : (B)), (bit)))

// stage 8 batches x 512 h (16 KB, contiguous) — round-8-proven scalar form
#define STAGE(PAR)                                                              \
  { const float* srcp = hbuf + (PAR) * HBUF_N + (size_t)b0 * HD;                \
    float vv[NBB];                                                              \
    _Pragma("unroll") for (int i = 0; i < NBB; ++i)                             \
      vv[i] = H_LOAD(srcp + i * HD + tid);                                      \
    _Pragma("unroll") for (int i = 0; i < NBB; ++i) hs[i][tid] = vv[i]; }

// group barrier: 1 flag store + 32-lane parallel poll (no atomics, no fences)
#define GBAR()                                                                  \
  { __syncthreads();                                                            \
    ++phase;                                                                    \
    if (tid == 0) H_STORE(myflag, phase);                                       \
    if (tid < GBLK) {                                                           \
      const int* sl = gflags + tid * SLOTP;                                     \
      while (H_LOAD(sl) < phase) __builtin_amdgcn_s_sleep(2);                   \
    }                                                                           \
    __syncthreads(); }

// One GRU step for the (16u x 8b) slice. Thread: unit u, k-slice kq (16 k).
// wW2[g][2i],[2i+1] = Wh[g*512+ur][4kq+128i ..] as packed pairs.
// Merged butterfly leaves lane l holding gate sums for batch l&7.
#define STEP(XV, WBUF)                                                          \
  { float a_[3][NBB];                                                           \
    _Pragma("unroll") for (int b = 0; b < NBB; ++b) {                           \
      v4f hb0 = *(const v4f*)&hs[b][4 * kq];                                    \
      v4f hb1 = *(const v4f*)&hs[b][4 * kq + 128];                              \
      v4f hb2 = *(const v4f*)&hs[b][4 * kq + 256];                              \
      v4f hb3 = *(const v4f*)&hs[b][4 * kq + 384];                              \
      _Pragma("unroll") for (int g = 0; g < 3; ++g) {                           \
        v2f t = pkmul(wW2[g][0], vlo(hb0));                                     \
        t = pkfma(wW2[g][1], vhi(hb0), t);                                      \
        t = pkfma(wW2[g][2], vlo(hb1), t);                                      \
        t = pkfma(wW2[g][3], vhi(hb1), t);                                      \
        t = pkfma(wW2[g][4], vlo(hb2), t);                                      \
        t = pkfma(wW2[g][5], vhi(hb2), t);                                      \
        t = pkfma(wW2[g][6], vlo(hb3), t);                                      \
        t = pkfma(wW2[g][7], vhi(hb3), t);                                      \
        a_[g][b] = t.x + t.y;                                                   \
      } }                                                                       \
    float r_[3];                                                                \
    _Pragma("unroll") for (int g = 0; g < 3; ++g) {                             \
      const float m0 = MERGE(a_[g][0], a_[g][1], 1);                            \
      const float m1 = MERGE(a_[g][2], a_[g][3], 1);                            \
      const float m2 = MERGE(a_[g][4], a_[g][5], 1);                            \
      const float m3 = MERGE(a_[g][6], a_[g][7], 1);                            \
      const float n0 = MERGE(m0, m1, 2);                                        \
      const float n1 = MERGE(m2, m3, 2);                                        \
      float q = MERGE(n0, n1, 4);                                               \
      q += __shfl_xor(q, 8);                                                    \
      q += __shfl_xor(q, 16);                                                   \
      r_[g] = q;                                                                \
    }                                                                           \
    if (kq < NBB) {                                                             \
      const float xv = (XV);                                                    \
      const float r = sigm(fmaf(xv, wi_r, c_r) + r_[0]);                        \
      const float z = sigm(fmaf(xv, wi_z, c_z) + r_[1]);                        \
      const float n = tanhf(fmaf(xv, wi_n, bi_n) + r * (r_[2] + bh_n));         \
      const float hp = hs[kq][ur];                                              \
      H_STORE((WBUF) + (size_t)(b0 + kq) * HD + ur, fmaf(z, hp - n, n));        \
    } }

__global__ __launch_bounds__(NTHR, 2) void gru_persist(
    const float* __restrict__ x,
    const float* __restrict__ eWi, const float* __restrict__ eWh,
    const float* __restrict__ ebi, const float* __restrict__ ebh,
    const float* __restrict__ dWi, const float* __restrict__ dWh,
    const float* __restrict__ dbi, const float* __restrict__ dbh,
    const float* __restrict__ linW, const float* __restrict__ linb,
    float* __restrict__ hbuf, int* __restrict__ sync_w,
    float* __restrict__ out)
{
    const int blk = blockIdx.x;
    const int g   = blk >> 5;          // batch group 0..15
    const int us  = blk & 31;          // unit slice 0..31
    const int b0  = g * NBB;
    const int u0  = us * NU;
    const int tid = threadIdx.x;
    const int u   = tid >> 5;          // 0..15 unit
    const int kq  = tid & 31;          // k lane
    const int ur  = u0 + u;

    __shared__ float hs[NBB][HD];      // staged h (8 x 512)
    __shared__ float xs[NBB][HD];      // prestaged encoder inputs x[b][t]
    __shared__ float lin_s[HD];
    __shared__ float y_s[NBB];

    int* gflags = sync_w + g * GBLK * SLOTP;
    int* myflag = gflags + us * SLOTP;
    int  phase  = 0;

    // encoder Wh fragment -> VGPRs as packed pairs (decoder loaded later)
    v2f wW2[3][8];
    #pragma unroll
    for (int g3 = 0; g3 < 3; ++g3) {
        const size_t row = (size_t)(g3 * HD + ur) * HD;
        #pragma unroll
        for (int i = 0; i < 4; ++i) {
            const v4f w = *(const v4f*)&eWh[row + i * 128 + 4 * kq];
            wW2[g3][2 * i]     = vlo(w);
            wW2[g3][2 * i + 1] = vhi(w);
        }
    }
    float wi_r = eWi[ur], wi_z = eWi[HD + ur], wi_n = eWi[2 * HD + ur];
    float c_r  = ebi[ur] + ebh[ur];
    float c_z  = ebi[HD + ur] + ebh[HD + ur];
    float bi_n = ebi[2 * HD + ur], bh_n = ebh[2 * HD + ur];
    lin_s[tid] = linW[tid];
    const float lb = linb[0];
    #pragma unroll
    for (int i = 0; i < NBB; ++i)       // prestage this group's x rows (16 KB)
        xs[i][tid] = x[(size_t)(b0 + i) * TT + tid];

    // ---------------- encoder ----------------
    for (int s = 0; s < TT; ++s) {
        if (s == 0) {
            #pragma unroll
            for (int i = 0; i < NBB; ++i) hs[i][tid] = 0.f;
        } else {
            STAGE((s + 1) & 1);
        }
        __syncthreads();
        STEP(xs[kq][s], hbuf + (s & 1) * HBUF_N);
        GBAR();
    }

    // switch to decoder weights/params
    #pragma unroll
    for (int g3 = 0; g3 < 3; ++g3) {
        const size_t row = (size_t)(g3 * HD + ur) * HD;
        #pragma unroll
        for (int i = 0; i < 4; ++i) {
            const v4f w = *(const v4f*)&dWh[row + i * 128 + 4 * kq];
            wW2[g3][2 * i]     = vlo(w);
            wW2[g3][2 * i + 1] = vhi(w);
        }
    }
    wi_r = dWi[ur]; wi_z = dWi[HD + ur]; wi_n = dWi[2 * HD + ur];
    c_r  = dbi[ur] + dbh[ur];
    c_z  = dbi[HD + ur] + dbh[HD + ur];
    bi_n = dbi[2 * HD + ur]; bh_n = dbh[2 * HD + ur];

    // ---------------- decoder ----------------
    for (int s = 0; s <= TT; ++s) {
        STAGE((s + 1) & 1);
        __syncthreads();
        // y[b] = hs[b] . linW + lb  (8 batches x 64-lane dot, redundant/block)
        {
            const int b = tid >> 6, k64 = tid & 63;
            float p = 0.f;
            #pragma unroll
            for (int i = 0; i < 2; ++i) {
                const float4 hv = *(const float4*)&hs[b][4 * k64 + 256 * i];
                const float4 lv = *(const float4*)&lin_s[4 * k64 + 256 * i];
                p = fmaf(hv.x, lv.x, p); p = fmaf(hv.y, lv.y, p);
                p = fmaf(hv.z, lv.z, p); p = fmaf(hv.w, lv.w, p);
            }
            p += __shfl_xor(p, 1);  p += __shfl_xor(p, 2);  p += __shfl_xor(p, 4);
            p += __shfl_xor(p, 8);  p += __shfl_xor(p, 16); p += __shfl_xor(p, 32);
            if (k64 == 0) y_s[b] = p + lb;
        }
        __syncthreads();
        if (s >= 1 && us == 0 && tid < NBB)
            out[(size_t)(b0 + tid) * TT + (TT - s)] = y_s[tid];
        if (s < TT) {
            STEP(y_s[kq], hbuf + (s & 1) * HBUF_N);
            GBAR();
        }
    }
}

extern "C" void kernel_launch(void* const* d_in, const int* in_sizes, int n_in,
                              void* d_out, int out_size, void* d_ws, size_t ws_size,
                              hipStream_t stream) {
    const float* x    = (const float*)d_in[0];
    const float* eWi  = (const float*)d_in[1];
    const float* eWh  = (const float*)d_in[2];
    const float* ebi  = (const float*)d_in[3];
    const float* ebh  = (const float*)d_in[4];
    const float* dWi  = (const float*)d_in[5];
    const float* dWh  = (const float*)d_in[6];
    const float* dbi  = (const float*)d_in[7];
    const float* dbh  = (const float*)d_in[8];
    const float* linW = (const float*)d_in[9];
    const float* linb = (const float*)d_in[10];
    float* out  = (float*)d_out;

    float* hbuf   = (float*)d_ws;                 // 2 x 256 KB h double-buffer
    int*   sync_w = (int*)(hbuf + 2 * HBUF_N);    // 16 x 32 x 256 B flag slots

    init_sync<<<32, 1024, 0, stream>>>(sync_w);
    gru_persist<<<dim3(NBLK), dim3(NTHR), 0, stream>>>(
        x, eWi, eWh, ebi, ebh, dWi, dWh, dbi, dbh, linW, linb,
        hbuf, sync_w, out);
}